// Round 1
// baseline (334.303 us; speedup 1.0000x reference)
//
#include <hip/hip_runtime.h>
#include <math.h>

#define NROWS 8192
#define DDIM  128
#define TI    64
#define TJ    64
#define JCHUNKS 4
#define JPER  (NROWS / JCHUNKS)   // 2048
#define NJT   (JPER / TJ)         // 32 j-tiles per chunk
#define ITILES (NROWS / TI)       // 128

// ---------------- kernel 1: L2 row-normalize f1 and f2 ----------------
__global__ void norm_kernel(const float* __restrict__ f1,
                            const float* __restrict__ f2,
                            float* __restrict__ f1n,
                            float* __restrict__ f2n) {
    int b = blockIdx.x;                 // 0..2N-1
    int row = b & (NROWS - 1);
    const float* src = (b < NROWS) ? f1 : f2;
    float*       dst = (b < NROWS) ? f1n : f2n;
    int t = threadIdx.x;                // 0..63
    float x0 = src[row * DDIM + t];
    float x1 = src[row * DDIM + t + 64];
    float s = x0 * x0 + x1 * x1;
    for (int off = 32; off; off >>= 1) s += __shfl_xor(s, off, 64);
    float inv = 1.0f / fmaxf(sqrtf(s), 1e-12f);
    dst[row * DDIM + t]      = x0 * inv;
    dst[row * DDIM + t + 64] = x1 * inv;
}

// ---------------- kernel 2: tiled dot + per-row additive stats ----------------
// stats per row: [Z, Zn, Cp, Qn, np]
__global__ __launch_bounds__(256) void stats_kernel(
    const float* __restrict__ f1n, const float* __restrict__ f2n,
    const float* __restrict__ targets, float* __restrict__ partials) {
  __shared__ float f1s[DDIM][TI];   // k-major: f1s[k][i_local]  (32 KB)
  __shared__ float f2s[DDIM][TJ];   // k-major: f2s[k][j_local]  (32 KB)

  const int itile = blockIdx.x;     // 0..127
  const int chunk = blockIdx.y;     // 0..3
  const int i0 = itile * TI;
  const int j0 = chunk * JPER;

  const int t = threadIdx.x;
  const int rowg = t >> 4;          // 0..15 -> rows 4*rowg..4*rowg+3
  const int colg = t & 15;          // 0..15 -> cols 4*colg..4*colg+3

  // stage f1 tile transposed: f1n[i0+c][k] -> f1s[k][c]
  for (int idx = t; idx < TI * (DDIM / 4); idx += 256) {
    int c  = idx & (TI - 1);
    int kq = idx >> 6;              // 0..31
    float4 v = *(const float4*)&f1n[(i0 + c) * DDIM + 4 * kq];
    f1s[4 * kq + 0][c] = v.x; f1s[4 * kq + 1][c] = v.y;
    f1s[4 * kq + 2][c] = v.z; f1s[4 * kq + 3][c] = v.w;
  }

  float ti_[4];
  #pragma unroll
  for (int rr = 0; rr < 4; ++rr) ti_[rr] = targets[i0 + 4 * rowg + rr];

  float Z[4]  = {0, 0, 0, 0};
  float Zn[4] = {0, 0, 0, 0};
  float Cp[4] = {0, 0, 0, 0};
  float Qn[4] = {0, 0, 0, 0};
  float Np[4] = {0, 0, 0, 0};

  for (int jt = 0; jt < NJT; ++jt) {
    const int jb = j0 + jt * TJ;
    __syncthreads();   // previous iteration done reading f2s
    for (int idx = t; idx < TJ * (DDIM / 4); idx += 256) {
      int c  = idx & (TJ - 1);
      int kq = idx >> 6;
      float4 v = *(const float4*)&f2n[(jb + c) * DDIM + 4 * kq];
      f2s[4 * kq + 0][c] = v.x; f2s[4 * kq + 1][c] = v.y;
      f2s[4 * kq + 2][c] = v.z; f2s[4 * kq + 3][c] = v.w;
    }
    __syncthreads();

    float acc[4][4] = {};
    #pragma unroll 8
    for (int k = 0; k < DDIM; ++k) {
      float4 a = *(const float4*)&f1s[k][4 * rowg];
      float4 b = *(const float4*)&f2s[k][4 * colg];
      float av[4] = {a.x, a.y, a.z, a.w};
      float bv[4] = {b.x, b.y, b.z, b.w};
      #pragma unroll
      for (int rr = 0; rr < 4; ++rr)
        #pragma unroll
        for (int cc = 0; cc < 4; ++cc)
          acc[rr][cc] = fmaf(av[rr], bv[cc], acc[rr][cc]);
    }

    float tj_[4];
    #pragma unroll
    for (int cc = 0; cc < 4; ++cc) tj_[cc] = targets[jb + 4 * colg + cc];

    #pragma unroll
    for (int rr = 0; rr < 4; ++rr) {
      const float tiv = ti_[rr];
      const bool pos_i = tiv > 0.0f;
      #pragma unroll
      for (int cc = 0; cc < 4; ++cc) {
        float cv = acc[rr][cc];
        float e  = __expf(cv - 1.0f);
        Z[rr] += e;
        float tjv = tj_[cc];
        bool neg = (fabsf(tiv - tjv) > 0.1f) || (pos_i != (tjv > 0.0f));
        if (neg) { Zn[rr] += e; Qn[rr] += e * e; }
        else     { Cp[rr] += cv; Np[rr] += 1.0f; }
      }
    }
  }

  // merge across the 16 lanes (colg) that share each row
  #pragma unroll
  for (int rr = 0; rr < 4; ++rr) {
    for (int off = 1; off < 16; off <<= 1) {
      Z[rr]  += __shfl_xor(Z[rr],  off, 64);
      Zn[rr] += __shfl_xor(Zn[rr], off, 64);
      Cp[rr] += __shfl_xor(Cp[rr], off, 64);
      Qn[rr] += __shfl_xor(Qn[rr], off, 64);
      Np[rr] += __shfl_xor(Np[rr], off, 64);
    }
  }
  if (colg == 0) {
    #pragma unroll
    for (int rr = 0; rr < 4; ++rr) {
      int r = i0 + 4 * rowg + rr;
      float* p = &partials[(r * JCHUNKS + chunk) * 5];
      p[0] = Z[rr]; p[1] = Zn[rr]; p[2] = Cp[rr]; p[3] = Qn[rr]; p[4] = Np[rr];
    }
  }
}

// ---------------- kernel 3: per-row loss + per-block partial sums ----------------
__global__ void finalize_rows(const float* __restrict__ partials,
                              float* __restrict__ blocksums) {
  int r = blockIdx.x * 256 + threadIdx.x;   // grid 32 x 256
  float Z = 0, Zn = 0, Cp = 0, Qn = 0, Np = 0;
  for (int ch = 0; ch < JCHUNKS; ++ch) {
    const float* p = &partials[(r * JCHUNKS + ch) * 5];
    Z += p[0]; Zn += p[1]; Cp += p[2]; Qn += p[3]; Np += p[4];
  }
  float nn   = (float)NROWS - Np;
  float lse  = 1.0f + logf(Z);
  float spos = lse - Cp / Np;
  float invZ = 1.0f / Z;
  float sneg = Zn * invZ + 0.5f * Qn * invZ * invZ - nn * 1e-10f;
  float per_row = spos + sneg / nn;

  float v = per_row;
  for (int off = 32; off; off >>= 1) v += __shfl_xor(v, off, 64);
  __shared__ float wsum[4];
  int lane = threadIdx.x & 63, wid = threadIdx.x >> 6;
  if (lane == 0) wsum[wid] = v;
  __syncthreads();
  if (threadIdx.x == 0)
    blocksums[blockIdx.x] = wsum[0] + wsum[1] + wsum[2] + wsum[3];
}

// ---------------- kernel 4: final mean ----------------
__global__ void final_sum(const float* __restrict__ blocksums,
                          float* __restrict__ out) {
  int t = threadIdx.x;  // 64
  float v = (t < 32) ? blocksums[t] : 0.0f;
  for (int off = 32; off; off >>= 1) v += __shfl_xor(v, off, 64);
  if (t == 0) out[0] = v * (1.0f / (float)NROWS);
}

// ---------------- launch ----------------
extern "C" void kernel_launch(void* const* d_in, const int* in_sizes, int n_in,
                              void* d_out, int out_size, void* d_ws, size_t ws_size,
                              hipStream_t stream) {
  const float* f1  = (const float*)d_in[0];
  const float* f2  = (const float*)d_in[1];
  const float* tgt = (const float*)d_in[2];
  float* out = (float*)d_out;

  float* ws   = (float*)d_ws;
  float* f1n  = ws;                                   // N*D floats
  float* f2n  = f1n + (size_t)NROWS * DDIM;           // N*D floats
  float* partials  = f2n + (size_t)NROWS * DDIM;      // N*JCHUNKS*5 floats
  float* blocksums = partials + (size_t)NROWS * JCHUNKS * 5;  // 32 floats

  norm_kernel<<<2 * NROWS, 64, 0, stream>>>(f1, f2, f1n, f2n);
  dim3 g2(ITILES, JCHUNKS);
  stats_kernel<<<g2, 256, 0, stream>>>(f1n, f2n, tgt, partials);
  finalize_rows<<<NROWS / 256, 256, 0, stream>>>(partials, blocksums);
  final_sum<<<1, 64, 0, stream>>>(blocksums, out);
}

// Round 2
// 137.531 us; speedup vs baseline: 2.4308x; 2.4308x over previous
//
#include <hip/hip_runtime.h>
#include <hip/hip_bf16.h>
#include <math.h>

#define NROWS 8192
#define DDIM  128
#define JCHUNKS 16
#define JPER  (NROWS / JCHUNKS)        // 512 cols per chunk
#define NCT   (JPER / 16)              // 32 col-tiles of 16
#define ROWS_PER_BLOCK 128             // 4 waves x 32 rows
#define GRIDX (NROWS / ROWS_PER_BLOCK) // 64

typedef __attribute__((ext_vector_type(8))) short bf16x8;  // 8 bf16 = 4 VGPRs
typedef __attribute__((ext_vector_type(4))) float f32x4;

// ---------------- kernel 1: L2 row-normalize -> bf16 ----------------
__global__ void norm_kernel(const float* __restrict__ f1,
                            const float* __restrict__ f2,
                            __hip_bfloat16* __restrict__ f1b,
                            __hip_bfloat16* __restrict__ f2b) {
    int b = blockIdx.x;                 // 0..2N-1
    int row = b & (NROWS - 1);
    const float* src = (b < NROWS) ? f1 : f2;
    __hip_bfloat16* dst = (b < NROWS) ? f1b : f2b;
    int t = threadIdx.x;                // 0..63
    float x0 = src[row * DDIM + t];
    float x1 = src[row * DDIM + t + 64];
    float s = x0 * x0 + x1 * x1;
    for (int off = 32; off; off >>= 1) s += __shfl_xor(s, off, 64);
    float inv = 1.0f / fmaxf(sqrtf(s), 1e-12f);
    dst[row * DDIM + t]      = __float2bfloat16(x0 * inv);
    dst[row * DDIM + t + 64] = __float2bfloat16(x1 * inv);
}

// ---------------- kernel 2: MFMA cos grid + fused stats epilogue ----------------
// per-row stats: [Z, Zn, Cp, Qn, Np]
__global__ __launch_bounds__(256, 4) void stats_kernel(
    const __hip_bfloat16* __restrict__ f1b,
    const __hip_bfloat16* __restrict__ f2b,
    const float* __restrict__ targets,
    float* __restrict__ partials) {
  const int chunk = blockIdx.y;                  // 0..15
  const int i0 = blockIdx.x * ROWS_PER_BLOCK;    // block's 128 rows
  const int w    = threadIdx.x >> 6;             // wave 0..3
  const int lane = threadIdx.x & 63;
  const int l15  = lane & 15;
  const int quad = lane >> 4;
  const int rbase = i0 + w * 32;                 // wave's 32 rows

  // A fragments, resident for the whole j-sweep: 2 row-sets x 4 k-steps
  // A layout (16x16x32): lane holds A[m=lane&15][k = quad*8 + j], j in [0,8)
  bf16x8 afrag[2][4];
  #pragma unroll
  for (int rs = 0; rs < 2; ++rs) {
    const __hip_bfloat16* arow =
        &f1b[(size_t)(rbase + rs * 16 + l15) * DDIM + quad * 8];
    #pragma unroll
    for (int ks = 0; ks < 4; ++ks)
      afrag[rs][ks] = *(const bf16x8*)(arow + ks * 32);
  }

  // C/D layout rows owned by this lane: row = rs*16 + quad*4 + rr
  float ti[8], pi[8];
  #pragma unroll
  for (int rs = 0; rs < 2; ++rs)
    #pragma unroll
    for (int rr = 0; rr < 4; ++rr) {
      float tv = targets[rbase + rs * 16 + quad * 4 + rr];
      ti[rs * 4 + rr] = tv;
      pi[rs * 4 + rr] = tv > 0.0f ? 1.0f : 0.0f;
    }

  float Z[8]  = {0,0,0,0,0,0,0,0};
  float Zn[8] = {0,0,0,0,0,0,0,0};
  float Qn[8] = {0,0,0,0,0,0,0,0};
  float Cp[8] = {0,0,0,0,0,0,0,0};
  float Np[8] = {0,0,0,0,0,0,0,0};

  const int jb0 = chunk * JPER;
  for (int ct = 0; ct < NCT; ++ct) {
    const int jb = jb0 + ct * 16;
    // B layout: lane holds B[k=quad*8+j][n=lane&15] = f2b[n][quad*8+j]
    const __hip_bfloat16* brow =
        &f2b[(size_t)(jb + l15) * DDIM + quad * 8];
    f32x4 acc0 = {0.f, 0.f, 0.f, 0.f};
    f32x4 acc1 = {0.f, 0.f, 0.f, 0.f};
    #pragma unroll
    for (int ks = 0; ks < 4; ++ks) {
      bf16x8 bfrag = *(const bf16x8*)(brow + ks * 32);
      acc0 = __builtin_amdgcn_mfma_f32_16x16x32_bf16(afrag[0][ks], bfrag, acc0, 0, 0, 0);
      acc1 = __builtin_amdgcn_mfma_f32_16x16x32_bf16(afrag[1][ks], bfrag, acc1, 0, 0, 0);
    }
    float tj = targets[jb + l15];
    float pj = tj > 0.0f ? 1.0f : 0.0f;
    #pragma unroll
    for (int rs = 0; rs < 2; ++rs)
      #pragma unroll
      for (int rr = 0; rr < 4; ++rr) {
        int r = rs * 4 + rr;
        float c = (rs == 0) ? acc0[rr] : acc1[rr];
        float e = __expf(c - 1.0f);
        Z[r] += e;
        bool pos = (fabsf(ti[r] - tj) <= 0.1f) & (pi[r] == pj);
        float en = pos ? 0.0f : e;
        Zn[r] += en;
        Qn[r] = fmaf(en, e, Qn[r]);
        Cp[r] += pos ? c : 0.0f;
        Np[r] += pos ? 1.0f : 0.0f;
      }
  }

  // reduce over the 16 lanes (l15) sharing each row
  #pragma unroll
  for (int r = 0; r < 8; ++r) {
    for (int off = 1; off < 16; off <<= 1) {
      Z[r]  += __shfl_xor(Z[r],  off, 64);
      Zn[r] += __shfl_xor(Zn[r], off, 64);
      Qn[r] += __shfl_xor(Qn[r], off, 64);
      Cp[r] += __shfl_xor(Cp[r], off, 64);
      Np[r] += __shfl_xor(Np[r], off, 64);
    }
  }
  if (l15 == 0) {
    #pragma unroll
    for (int r = 0; r < 8; ++r) {
      int row = rbase + (r >> 2) * 16 + quad * 4 + (r & 3);
      float* p = &partials[((size_t)row * JCHUNKS + chunk) * 5];
      p[0] = Z[r]; p[1] = Zn[r]; p[2] = Cp[r]; p[3] = Qn[r]; p[4] = Np[r];
    }
  }
}

// ---------------- kernel 3: per-row loss + per-block partial sums ----------------
__global__ void finalize_rows(const float* __restrict__ partials,
                              float* __restrict__ blocksums) {
  int r = blockIdx.x * 256 + threadIdx.x;   // grid 32 x 256
  float Z = 0, Zn = 0, Cp = 0, Qn = 0, Np = 0;
  for (int ch = 0; ch < JCHUNKS; ++ch) {
    const float* p = &partials[((size_t)r * JCHUNKS + ch) * 5];
    Z += p[0]; Zn += p[1]; Cp += p[2]; Qn += p[3]; Np += p[4];
  }
  float nn   = (float)NROWS - Np;
  float lse  = 1.0f + logf(Z);
  float spos = lse - Cp / Np;
  float invZ = 1.0f / Z;
  float sneg = Zn * invZ + 0.5f * Qn * invZ * invZ - nn * 1e-10f;
  float per_row = spos + sneg / nn;

  float v = per_row;
  for (int off = 32; off; off >>= 1) v += __shfl_xor(v, off, 64);
  __shared__ float wsum[4];
  int lane = threadIdx.x & 63, wid = threadIdx.x >> 6;
  if (lane == 0) wsum[wid] = v;
  __syncthreads();
  if (threadIdx.x == 0)
    blocksums[blockIdx.x] = wsum[0] + wsum[1] + wsum[2] + wsum[3];
}

// ---------------- kernel 4: final mean ----------------
__global__ void final_sum(const float* __restrict__ blocksums,
                          float* __restrict__ out) {
  int t = threadIdx.x;  // 64
  float v = (t < 32) ? blocksums[t] : 0.0f;
  for (int off = 32; off; off >>= 1) v += __shfl_xor(v, off, 64);
  if (t == 0) out[0] = v * (1.0f / (float)NROWS);
}

// ---------------- launch ----------------
extern "C" void kernel_launch(void* const* d_in, const int* in_sizes, int n_in,
                              void* d_out, int out_size, void* d_ws, size_t ws_size,
                              hipStream_t stream) {
  const float* f1  = (const float*)d_in[0];
  const float* f2  = (const float*)d_in[1];
  const float* tgt = (const float*)d_in[2];
  float* out = (float*)d_out;

  char* ws = (char*)d_ws;
  __hip_bfloat16* f1b = (__hip_bfloat16*)ws;                       // 2 MB
  __hip_bfloat16* f2b = (__hip_bfloat16*)(ws + (size_t)NROWS * DDIM * 2);
  float* partials  = (float*)(ws + (size_t)NROWS * DDIM * 4);      // N*16*5 floats
  float* blocksums = partials + (size_t)NROWS * JCHUNKS * 5;       // 32 floats

  norm_kernel<<<2 * NROWS, 64, 0, stream>>>(f1, f2, f1b, f2b);
  dim3 g2(GRIDX, JCHUNKS);
  stats_kernel<<<g2, 256, 0, stream>>>(f1b, f2b, tgt, partials);
  finalize_rows<<<NROWS / 256, 256, 0, stream>>>(partials, blocksums);
  final_sum<<<1, 64, 0, stream>>>(blocksums, out);
}

// Round 3
// 133.428 us; speedup vs baseline: 2.5055x; 1.0307x over previous
//
#include <hip/hip_runtime.h>
#include <hip/hip_bf16.h>
#include <math.h>

#define NROWS 8192
#define DDIM  128
#define JCHUNKS 16
#define JPER  (NROWS / JCHUNKS)        // 512 cols per chunk
#define NCT   (JPER / 16)              // 32 col-tiles of 16
#define ROWS_PER_BLOCK 128             // 4 waves x 32 rows
#define GRIDX (NROWS / ROWS_PER_BLOCK) // 64
#define LOG2E 1.44269504088896f

typedef __attribute__((ext_vector_type(8))) short bf16x8;  // 8 bf16 = 4 VGPRs
typedef __attribute__((ext_vector_type(4))) float f32x4;
typedef __attribute__((ext_vector_type(2))) float f32x2;

// ---------------- kernel 1: L2 row-normalize -> bf16 (float4 loads) ----------------
__global__ __launch_bounds__(256) void norm_kernel(
    const float* __restrict__ f1, const float* __restrict__ f2,
    __hip_bfloat16* __restrict__ f1b, __hip_bfloat16* __restrict__ f2b) {
  int t = threadIdx.x;
  int rloc = t >> 5;                 // 0..7, row within block
  int l = t & 31;                    // 32 lanes per row, float4 each
  int b = blockIdx.x;                // 0..2047
  int half = (b >= NROWS / 8) ? 1 : 0;
  int row = (b - half * (NROWS / 8)) * 8 + rloc;
  const float* src = half ? f2 : f1;
  __hip_bfloat16* dst = half ? f2b : f1b;

  float4 v = ((const float4*)src)[row * (DDIM / 4) + l];
  float s = v.x * v.x + v.y * v.y + v.z * v.z + v.w * v.w;
  #pragma unroll
  for (int off = 1; off < 32; off <<= 1) s += __shfl_xor(s, off, 64); // stays in 32-group
  float inv = 1.0f / fmaxf(sqrtf(s), 1e-12f);
  __hip_bfloat16 hv[4];
  hv[0] = __float2bfloat16(v.x * inv);
  hv[1] = __float2bfloat16(v.y * inv);
  hv[2] = __float2bfloat16(v.z * inv);
  hv[3] = __float2bfloat16(v.w * inv);
  *(ushort4*)&dst[(size_t)row * DDIM + l * 4] = *(ushort4*)hv;
}

// ---------------- kernel 2: MFMA cos grid + fused packed stats ----------------
// per-row stats: [Z, Zp, Cp, Np]   (Zn = Z - Zp in finalize; Qn dropped: <=4e-7 error)
__global__ __launch_bounds__(256, 3) void stats_kernel(
    const __hip_bfloat16* __restrict__ f1b,
    const __hip_bfloat16* __restrict__ f2b,
    const float* __restrict__ targets,
    float* __restrict__ partials) {
  const int chunk = blockIdx.y;                  // 0..15
  const int i0 = blockIdx.x * ROWS_PER_BLOCK;
  const int w    = threadIdx.x >> 6;
  const int lane = threadIdx.x & 63;
  const int l15  = lane & 15;
  const int quad = lane >> 4;
  const int rbase = i0 + w * 32;

  // A fragments resident for whole sweep: A[m=lane&15][k=quad*8+j]
  bf16x8 afrag[2][4];
  #pragma unroll
  for (int rs = 0; rs < 2; ++rs) {
    const __hip_bfloat16* arow =
        &f1b[(size_t)(rbase + rs * 16 + l15) * DDIM + quad * 8];
    #pragma unroll
    for (int ks = 0; ks < 4; ++ks)
      afrag[rs][ks] = *(const bf16x8*)(arow + ks * 32);
  }

  // lane's C rows: comp0 = quad*4+rr, comp1 = 16+quad*4+rr
  f32x2 ti2[4];
  #pragma unroll
  for (int rr = 0; rr < 4; ++rr) {
    ti2[rr][0] = targets[rbase + quad * 4 + rr];
    ti2[rr][1] = targets[rbase + 16 + quad * 4 + rr];
  }

  f32x2 Z2[4]  = {{0,0},{0,0},{0,0},{0,0}};
  f32x2 Zp2[4] = {{0,0},{0,0},{0,0},{0,0}};
  f32x2 Cp2[4] = {{0,0},{0,0},{0,0},{0,0}};
  f32x2 Np2[4] = {{0,0},{0,0},{0,0},{0,0}};

  const int jb0 = chunk * JPER;
  const __hip_bfloat16* bbase = &f2b[(size_t)(jb0 + l15) * DDIM + quad * 8];

  // prefetch first B tile + tj
  bf16x8 bf[4];
  #pragma unroll
  for (int ks = 0; ks < 4; ++ks) bf[ks] = *(const bf16x8*)(bbase + ks * 32);
  float tj = targets[jb0 + l15];

  for (int ct = 0; ct < NCT; ++ct) {
    f32x4 acc0 = {0.f, 0.f, 0.f, 0.f};
    f32x4 acc1 = {0.f, 0.f, 0.f, 0.f};
    #pragma unroll
    for (int ks = 0; ks < 4; ++ks) {
      acc0 = __builtin_amdgcn_mfma_f32_16x16x32_bf16(afrag[0][ks], bf[ks], acc0, 0, 0, 0);
      acc1 = __builtin_amdgcn_mfma_f32_16x16x32_bf16(afrag[1][ks], bf[ks], acc1, 0, 0, 0);
    }

    // prefetch next B tile + tj (hides under epilogue)
    bf16x8 bn[4] = {};
    float tjn = 0.0f;
    if (ct + 1 < NCT) {
      const __hip_bfloat16* p2 = bbase + (size_t)(ct + 1) * 16 * DDIM;
      #pragma unroll
      for (int ks = 0; ks < 4; ++ks) bn[ks] = *(const bf16x8*)(p2 + ks * 32);
      tjn = targets[jb0 + (ct + 1) * 16 + l15];
    }

    // fused packed epilogue
    const bool pj = tj > 0.0f;
    const f32x2 tjs = {tj, tj};
    const f32x2 Ks = {LOG2E, LOG2E};
    #pragma unroll
    for (int rr = 0; rr < 4; ++rr) {
      f32x2 c2 = {acc0[rr], acc1[rr]};
      f32x2 d2 = ti2[rr] - tjs;
      bool q0 = (__builtin_fabsf(d2[0]) <= 0.1f) & ((ti2[rr][0] > 0.0f) == pj);
      bool q1 = (__builtin_fabsf(d2[1]) <= 0.1f) & ((ti2[rr][1] > 0.0f) == pj);
      f32x2 m2 = {q0 ? 1.0f : 0.0f, q1 ? 1.0f : 0.0f};
      f32x2 x2 = c2 * Ks - Ks;                         // log2(e^(c-1))
      f32x2 e2 = {__builtin_amdgcn_exp2f(x2[0]), __builtin_amdgcn_exp2f(x2[1])};
      Z2[rr]  += e2;
      Zp2[rr] += m2 * e2;
      Cp2[rr] += m2 * c2;
      Np2[rr] += m2;
    }

    #pragma unroll
    for (int ks = 0; ks < 4; ++ks) bf[ks] = bn[ks];
    tj = tjn;
  }

  // reduce over the 16 lanes (l15) sharing each row
  #pragma unroll
  for (int rr = 0; rr < 4; ++rr) {
    for (int off = 1; off < 16; off <<= 1) {
      Z2[rr][0]  += __shfl_xor(Z2[rr][0],  off, 64);
      Z2[rr][1]  += __shfl_xor(Z2[rr][1],  off, 64);
      Zp2[rr][0] += __shfl_xor(Zp2[rr][0], off, 64);
      Zp2[rr][1] += __shfl_xor(Zp2[rr][1], off, 64);
      Cp2[rr][0] += __shfl_xor(Cp2[rr][0], off, 64);
      Cp2[rr][1] += __shfl_xor(Cp2[rr][1], off, 64);
      Np2[rr][0] += __shfl_xor(Np2[rr][0], off, 64);
      Np2[rr][1] += __shfl_xor(Np2[rr][1], off, 64);
    }
  }
  if (l15 == 0) {
    #pragma unroll
    for (int rs = 0; rs < 2; ++rs)
      #pragma unroll
      for (int rr = 0; rr < 4; ++rr) {
        int row = rbase + rs * 16 + quad * 4 + rr;
        float* p = &partials[((size_t)row * JCHUNKS + chunk) * 4];
        p[0] = Z2[rr][rs]; p[1] = Zp2[rr][rs]; p[2] = Cp2[rr][rs]; p[3] = Np2[rr][rs];
      }
  }
}

// ---------------- kernel 3: per-row loss + per-block partial sums ----------------
__global__ void finalize_rows(const float* __restrict__ partials,
                              float* __restrict__ blocksums) {
  int r = blockIdx.x * 256 + threadIdx.x;   // grid 32 x 256
  float Z = 0, Zp = 0, Cp = 0, Np = 0;
  for (int ch = 0; ch < JCHUNKS; ++ch) {
    const float* p = &partials[((size_t)r * JCHUNKS + ch) * 4];
    Z += p[0]; Zp += p[1]; Cp += p[2]; Np += p[3];
  }
  float Zn = Z - Zp;
  float nn = (float)NROWS - Np;
  float spos = (1.0f + logf(Z)) - Cp / Np;
  float sneg = Zn / Z - nn * 1e-10f;
  float per_row = spos + sneg / nn;

  float v = per_row;
  for (int off = 32; off; off >>= 1) v += __shfl_xor(v, off, 64);
  __shared__ float wsum[4];
  int lane = threadIdx.x & 63, wid = threadIdx.x >> 6;
  if (lane == 0) wsum[wid] = v;
  __syncthreads();
  if (threadIdx.x == 0)
    blocksums[blockIdx.x] = wsum[0] + wsum[1] + wsum[2] + wsum[3];
}

// ---------------- kernel 4: final mean ----------------
__global__ void final_sum(const float* __restrict__ blocksums,
                          float* __restrict__ out) {
  int t = threadIdx.x;  // 64
  float v = (t < 32) ? blocksums[t] : 0.0f;
  for (int off = 32; off; off >>= 1) v += __shfl_xor(v, off, 64);
  if (t == 0) out[0] = v * (1.0f / (float)NROWS);
}

// ---------------- launch ----------------
extern "C" void kernel_launch(void* const* d_in, const int* in_sizes, int n_in,
                              void* d_out, int out_size, void* d_ws, size_t ws_size,
                              hipStream_t stream) {
  const float* f1  = (const float*)d_in[0];
  const float* f2  = (const float*)d_in[1];
  const float* tgt = (const float*)d_in[2];
  float* out = (float*)d_out;

  char* ws = (char*)d_ws;
  __hip_bfloat16* f1b = (__hip_bfloat16*)ws;                       // 2 MB
  __hip_bfloat16* f2b = (__hip_bfloat16*)(ws + (size_t)NROWS * DDIM * 2);
  float* partials  = (float*)(ws + (size_t)NROWS * DDIM * 4);      // N*16*4 floats
  float* blocksums = partials + (size_t)NROWS * JCHUNKS * 4;       // 32 floats

  norm_kernel<<<2 * (NROWS / 8), 256, 0, stream>>>(f1, f2, f1b, f2b);
  dim3 g2(GRIDX, JCHUNKS);
  stats_kernel<<<g2, 256, 0, stream>>>(f1b, f2b, tgt, partials);
  finalize_rows<<<NROWS / 256, 256, 0, stream>>>(partials, blocksums);
  final_sum<<<1, 64, 0, stream>>>(blocksums, out);
}